// Round 1
// 610.258 us; speedup vs baseline: 1.0397x; 1.0397x over previous
//
#include <hip/hip_runtime.h>
#include <hip/hip_bf16.h>

typedef __attribute__((ext_vector_type(8))) short short8;     // 8 x bf16 (4 VGPRs)
typedef __attribute__((ext_vector_type(4))) float floatx4;    // MFMA accumulator / 16B load

static __device__ __forceinline__ unsigned f2bf(float f) {   // RNE f32->bf16 bits
    unsigned u = __builtin_bit_cast(unsigned, f);
    unsigned r = u + 0x7fffu + ((u >> 16) & 1u);
    return r >> 16;
}
// HW packed convert: dst.lo = bf16(lo), dst.hi = bf16(hi) (RNE). 1 VALU vs ~11.
static __device__ __forceinline__ unsigned pk2bf(float lo, float hi) {
    unsigned r;
    asm("v_cvt_pk_bf16_f32 %0, %1, %2" : "=v"(r) : "v"(lo), "v"(hi));
    return r;
}
static __device__ __forceinline__ floatx4 ntload(const floatx4* p) {
    return __builtin_nontemporal_load(p);   // x is stream-once: evict-first in L2
}

// ---------------------------------------------------------------------------
// Prep: T^T[d][k] (k = c*4 + rr*2 + q), u[d] = sum nw*W, v[d] = sum nb*W.
// Reference channel order is concat([ll,lh,hl,hh]) -> channel s*96+c.
// T[(c,rr,q)][d] = 0.5 * sum_s sign(s,(rr,q)) * nw[s*96+c] * W[s*96+c][d]
// ---------------------------------------------------------------------------
__global__ __launch_bounds__(384)
void prep_kernel(const float* __restrict__ nw,
                 const float* __restrict__ nb,
                 const float* __restrict__ W,    // [384][192] f32
                 __hip_bfloat16* __restrict__ Tt, // [192][384] bf16
                 float* __restrict__ uvec,
                 float* __restrict__ vvec)
{
    __shared__ float su[384];
    __shared__ float sv[384];
    const int d = blockIdx.x;     // 0..191
    const int t = threadIdx.x;    // 0..383

    const int c  = t >> 2;
    const int rr = (t >> 1) & 1;
    const int q  = t & 1;

    float w0 = W[(0 * 96 + c) * 192 + d];  // ll
    float w1 = W[(1 * 96 + c) * 192 + d];  // lh
    float w2 = W[(2 * 96 + c) * 192 + d];  // hl
    float w3 = W[(3 * 96 + c) * 192 + d];  // hh
    float n0 = nw[0 * 96 + c];
    float n1 = nw[1 * 96 + c];
    float n2 = nw[2 * 96 + c];
    float n3 = nw[3 * 96 + c];

    float slh = rr ? -1.f : 1.f;
    float shl = q  ? -1.f : 1.f;
    float shh = (rr ^ q) ? -1.f : 1.f;
    float tv = 0.5f * (n0 * w0 + slh * n1 * w1 + shl * n2 * w2 + shh * n3 * w3);
    ((unsigned short*)Tt)[d * 384 + t] = (unsigned short)f2bf(tv);

    float wt = W[t * 192 + d];
    su[t] = nw[t] * wt;
    sv[t] = nb[t] * wt;
    __syncthreads();
    if (t < 64) {
        float a = su[t] + su[t + 64] + su[t + 128] + su[t + 192] + su[t + 256] + su[t + 320];
        float b = sv[t] + sv[t + 64] + sv[t + 128] + sv[t + 192] + sv[t + 256] + sv[t + 320];
        for (int off = 32; off; off >>= 1) {
            a += __shfl_down(a, off);
            b += __shfl_down(b, off);
        }
        if (t == 0) { uvec[d] = a; vvec[d] = b; }
    }
}

// ---------------------------------------------------------------------------
// Main fused kernel. Block: 256 thr (4 waves), tile M=64 positions x N=192.
// LDS: As 50176 B + S12 2048 B = 52224 B -> 3 blocks/CU (launch_bounds(256,3)
// caps VGPR at 168 so occupancy is LDS-bound, not VGPR-bound).
// Staging: float4 nontemporal loads (16 B/lane), 2 positions x 12 channels
// per thread (ch = cg + 8*i). Stats per position via shfl_xor(32) + S12.
// GEMM: A = Tt rows (global, L2-hot; ks 0,1 preloaded before staging so the
// first MFMA has zero exposed latency), B = As rows via ds_read_b128.
// ---------------------------------------------------------------------------
__global__ __launch_bounds__(256, 3)
void fused_kernel(const float* __restrict__ x,
                  const __hip_bfloat16* __restrict__ Tt,
                  const float* __restrict__ uvec,
                  const float* __restrict__ vvec,
                  float* __restrict__ out)
{
    constexpr int PK = 392;                                // 784 B rows = 49*16B
    __shared__ __align__(16) __hip_bfloat16 As[64 * PK];   // 50176 B
    __shared__ __align__(16) float S12[4][32][4];          // 2048 B; ab aliased here

    const int t  = threadIdx.x;
    const int bi = blockIdx.x;
    const int mb = bi & 1;          // half of the w-row
    const int h  = (bi >> 1) & 127; // output row (half-res)
    const int b  = bi >> 8;         // batch

    const int lane = t & 63;
    const int wv   = t >> 6;
    const int l15  = lane & 15;
    const int q2   = lane >> 4;     // 0..3

    // A-frag base: Tt row d = wv*48 + l15 (+ dt*16), k-slice q2*8 + ks*32.
    // strides in short8 units: dt -> 768, ks -> 4
    const short8* Ap0 = (const short8*)(Tt + (size_t)(wv * 48 + l15) * 384 + q2 * 8);
    // Preload A for ks=0,1 BEFORE the stage loads: their vmcnt wait then does
    // not drain the staging queue, and L2 latency hides under HBM staging.
    short8 a0_0 = Ap0[0 * 768 + 0];
    short8 a0_1 = Ap0[1 * 768 + 0];
    short8 a0_2 = Ap0[2 * 768 + 0];
    short8 a1_0 = Ap0[0 * 768 + 4];
    short8 a1_1 = Ap0[1 * 768 + 4];
    short8 a1_2 = Ap0[2 * 768 + 4];

    // ---- stage x tile into LDS (bf16) + per-position LN stats (f32) ----
    {
        const int f  = t & 31;   // float4 index -> positions 2f, 2f+1
        const int cg = t >> 5;   // channel phase 0..7; thread owns ch = cg + 8*i
        const floatx4* xt =
            (const floatx4*)(x + ((size_t)b * 96 + cg) * 65536 + (size_t)(2 * h) * 256)
            + (mb * 32 + f);
        float s1a = 0.f, s2a = 0.f, s1b = 0.f, s2b = 0.f;
#pragma unroll
        for (int i = 0; i < 12; ++i) {
            const floatx4* p = xt + (size_t)i * 131072;   // +8 channels
            floatx4 v = ntload(p);        // row 2h   : a0 b0 a1 b1
            floatx4 u = ntload(p + 64);   // row 2h+1 : c0 d0 c1 d1
            s1a += v[0];                  // sum_k y = 2 * sum_c a
            s1b += v[2];
            s2a += v[0] * v[0] + v[1] * v[1] + u[0] * u[0] + u[1] * u[1];
            s2b += v[2] * v[2] + v[3] * v[3] + u[2] * u[2] + u[3] * u[3];
            const int col = (cg + 8 * i) * 4;             // shorts within row
            *(uint2*)(&As[(2 * f) * PK + col]) =
                make_uint2(pk2bf(v[0], v[1]), pk2bf(u[0], u[1]));
            *(uint2*)(&As[(2 * f + 1) * PK + col]) =
                make_uint2(pk2bf(v[2], v[3]), pk2bf(u[2], u[3]));
        }
        // combine cg pairs (lane l <-> l^32 share f, differ in cg parity)
        float r1a = s1a + __shfl_xor(s1a, 32);
        float r2a = s2a + __shfl_xor(s2a, 32);
        float r1b = s1b + __shfl_xor(s1b, 32);
        float r2b = s2b + __shfl_xor(s2b, 32);
        if (lane < 32) {
            *(floatx4*)&S12[wv][f][0] = (floatx4){r1a, r2a, r1b, r2b};
        }
    }
    __syncthreads();

    if (t < 64) {
        // per-position totals over the 4 waves; reads complete (in-order, single
        // wave) before ab is written into the same buffer.
        floatx4 r = *(const floatx4*)&S12[0][t >> 1][0];
        r += *(const floatx4*)&S12[1][t >> 1][0];
        r += *(const floatx4*)&S12[2][t >> 1][0];
        r += *(const floatx4*)&S12[3][t >> 1][0];
        float S1 = (t & 1) ? r[2] : r[0];
        float S2 = (t & 1) ? r[3] : r[1];
        float mu  = S1 * (2.0f / 384.0f);
        float var = S2 * (1.0f / 384.0f) - mu * mu;
        float rs  = rsqrtf(var + 1e-5f);
        ((float2*)S12)[t] = make_float2(rs, -rs * mu);   // ab[pos]
    }
    __syncthreads();

    // ---- epilogue vector preload (L2-hot; latency hides under GEMM) ----
    const int dbase = wv * 48 + q2 * 4;
    floatx4 uu[3], vv[3];
#pragma unroll
    for (int dt = 0; dt < 3; ++dt) {
        uu[dt] = *(const floatx4*)(uvec + dbase + dt * 16);
        vv[dt] = *(const floatx4*)(vvec + dbase + dt * 16);
    }
    float2 abv[4];
#pragma unroll
    for (int p = 0; p < 4; ++p) abv[p] = ((const float2*)S12)[p * 16 + l15];

    // ---- GEMM: per wave 3 d-tiles (48 cols) x 4 pos-tiles ----
    const short8* Bp0 = (const short8*)(&As[l15 * PK + q2 * 8]);  // p -> 784, ks -> 4

    floatx4 acc[3][4];
#pragma unroll
    for (int dt = 0; dt < 3; ++dt)
#pragma unroll
        for (int p = 0; p < 4; ++p)
            acc[dt][p] = (floatx4){0.f, 0.f, 0.f, 0.f};

    {   // ks = 0, 1 with preloaded A-frags
        short8 af[3] = {a0_0, a0_1, a0_2};
        short8 bf[4];
#pragma unroll
        for (int p = 0; p < 4; ++p) bf[p] = Bp0[p * 784 + 0];
#pragma unroll
        for (int dt = 0; dt < 3; ++dt)
#pragma unroll
            for (int p = 0; p < 4; ++p)
                acc[dt][p] = __builtin_amdgcn_mfma_f32_16x16x32_bf16(
                    af[dt], bf[p], acc[dt][p], 0, 0, 0);
        short8 ag[3] = {a1_0, a1_1, a1_2};
#pragma unroll
        for (int p = 0; p < 4; ++p) bf[p] = Bp0[p * 784 + 4];
#pragma unroll
        for (int dt = 0; dt < 3; ++dt)
#pragma unroll
            for (int p = 0; p < 4; ++p)
                acc[dt][p] = __builtin_amdgcn_mfma_f32_16x16x32_bf16(
                    ag[dt], bf[p], acc[dt][p], 0, 0, 0);
    }
#pragma unroll 2
    for (int ks = 2; ks < 12; ++ks) {
        short8 af[3], bf[4];
#pragma unroll
        for (int dt = 0; dt < 3; ++dt) af[dt] = Ap0[dt * 768 + ks * 4];
#pragma unroll
        for (int p = 0; p < 4; ++p) bf[p] = Bp0[p * 784 + ks * 4];
#pragma unroll
        for (int dt = 0; dt < 3; ++dt)
#pragma unroll
            for (int p = 0; p < 4; ++p)
                acc[dt][p] = __builtin_amdgcn_mfma_f32_16x16x32_bf16(
                    af[dt], bf[p], acc[dt][p], 0, 0, 0);
    }

    // ---- epilogue: C[d][pos] -> out[b][l][d] (f32), float4 per lane ----
    const size_t outbase = ((size_t)b * 16384 + (size_t)h * 128 + mb * 64) * 192;
#pragma unroll
    for (int dt = 0; dt < 3; ++dt) {
        const int drow = wv * 48 + dt * 16 + q2 * 4;
#pragma unroll
        for (int p = 0; p < 4; ++p) {
            const int pos = p * 16 + l15;
            const float al = abv[p].x, be = abv[p].y;
            floatx4 o;
            o[0] = al * acc[dt][p][0] + be * uu[dt][0] + vv[dt][0];
            o[1] = al * acc[dt][p][1] + be * uu[dt][1] + vv[dt][1];
            o[2] = al * acc[dt][p][2] + be * uu[dt][2] + vv[dt][2];
            o[3] = al * acc[dt][p][3] + be * uu[dt][3] + vv[dt][3];
            *(floatx4*)(out + outbase + (size_t)pos * 192 + drow) = o;
        }
    }
}

// ---------------------------------------------------------------------------
extern "C" void kernel_launch(void* const* d_in, const int* in_sizes, int n_in,
                              void* d_out, int out_size, void* d_ws, size_t ws_size,
                              hipStream_t stream)
{
    const float* x  = (const float*)d_in[0];
    const float* nw = (const float*)d_in[1];
    const float* nb = (const float*)d_in[2];
    const float* W  = (const float*)d_in[3];
    float* out = (float*)d_out;

    __hip_bfloat16* Tt = (__hip_bfloat16*)d_ws;                 // 192*384 bf16
    float* uvec = (float*)((char*)d_ws + 384 * 192 * 2);        // 192 f32
    float* vvec = uvec + 192;                                   // 192 f32

    prep_kernel<<<192, 384, 0, stream>>>(nw, nb, W, Tt, uvec, vvec);
    fused_kernel<<<4096, 256, 0, stream>>>(x, Tt, uvec, vvec, out);
}